// Round 1
// baseline (583.938 us; speedup 1.0000x reference)
//
#include <hip/hip_runtime.h>

#define IN_C 128
#define HID  32

// ---------------------------------------------------------------------------
// K1: r0 = relu(x @ w_embed)   x:[n,128] w:[128,32] -> r0:[n,32]
// 256 threads = 8 rows/block, one thread per (row, h), w_embed staged in LDS.
// ---------------------------------------------------------------------------
__global__ void embed_kernel(const float* __restrict__ x,
                             const float* __restrict__ w,
                             float* __restrict__ r0, int n) {
    __shared__ float wl[IN_C * HID];
    const int tid = threadIdx.x;
    for (int i = tid; i < IN_C * HID; i += blockDim.x) wl[i] = w[i];
    __syncthreads();
    const int row = blockIdx.x * (blockDim.x / HID) + tid / HID;
    const int h   = tid % HID;
    if (row >= n) return;
    const float* xr = x + (size_t)row * IN_C;
    float acc = 0.f;
#pragma unroll 8
    for (int k = 0; k < IN_C; ++k) acc += xr[k] * wl[k * HID + h];
    r0[(size_t)row * HID + h] = fmaxf(acc, 0.f);
}

// ---------------------------------------------------------------------------
// K2: CSR indptr from sorted row array via binary search (lower_bound).
// rows[] is sorted ascending (edge keys came from np.unique(r*n+c)).
// ---------------------------------------------------------------------------
__global__ void build_indptr(const int* __restrict__ rows, int nnz,
                             int* __restrict__ indptr, int n) {
    const int i = blockIdx.x * blockDim.x + threadIdx.x;
    if (i > n) return;
    int lo = 0, hi = nnz;
    while (lo < hi) {
        int mid = (lo + hi) >> 1;
        if (rows[mid] < i) lo = mid + 1; else hi = mid;
    }
    indptr[i] = lo;
}

// ---------------------------------------------------------------------------
// K3: row-group CSR SpMM + ReLU.
// C threads per destination row; lane f accumulates feature f in a register.
// out[row*out_stride + out_off + f] = relu(sum_e val[e] * xin[col[e]*C + f])
// ---------------------------------------------------------------------------
template <int C>
__global__ void spmm_relu(const int* __restrict__ indptr,
                          const int* __restrict__ col,
                          const float* __restrict__ val,
                          const float* __restrict__ xin,
                          float* __restrict__ out,
                          int out_stride, int out_off, int n) {
    const int row = blockIdx.x * (blockDim.x / C) + threadIdx.x / C;
    const int f   = threadIdx.x % C;
    if (row >= n) return;
    const int s = indptr[row];
    const int e = indptr[row + 1];
    float acc0 = 0.f, acc1 = 0.f;
    int i = s;
    for (; i + 1 < e; i += 2) {
        int   c0 = col[i],     c1 = col[i + 1];
        float v0 = val[i],     v1 = val[i + 1];
        acc0 += v0 * xin[(size_t)c0 * C + f];
        acc1 += v1 * xin[(size_t)c1 * C + f];
    }
    if (i < e) acc0 += val[i] * xin[(size_t)col[i] * C + f];
    out[(size_t)row * out_stride + out_off + f] = fmaxf(acc0 + acc1, 0.f);
}

// ---------------------------------------------------------------------------
// K4: out = [r0 | r1 | r2] @ w_classify   (fused concat; w in LDS)
// 16 threads per row (one per output col), 16 rows per 256-thread block.
// ---------------------------------------------------------------------------
#define CDIM 224
#define OUT_C 16
__global__ void classify_kernel(const float* __restrict__ r0,
                                const float* __restrict__ r1,
                                const float* __restrict__ r2,
                                const float* __restrict__ w,
                                float* __restrict__ out, int n) {
    __shared__ float wl[CDIM * OUT_C];
    const int tid = threadIdx.x;
    for (int i = tid; i < CDIM * OUT_C; i += blockDim.x) wl[i] = w[i];
    __syncthreads();
    const int row = blockIdx.x * (blockDim.x / OUT_C) + tid / OUT_C;
    const int o   = tid % OUT_C;
    if (row >= n) return;
    float acc = 0.f;
    const float* a = r0 + (size_t)row * 32;
#pragma unroll 8
    for (int j = 0; j < 32; ++j)  acc += a[j] * wl[j * OUT_C + o];
    const float* b = r1 + (size_t)row * 64;
#pragma unroll 8
    for (int j = 0; j < 64; ++j)  acc += b[j] * wl[(32 + j) * OUT_C + o];
    const float* c = r2 + (size_t)row * 128;
#pragma unroll 8
    for (int j = 0; j < 128; ++j) acc += c[j] * wl[(96 + j) * OUT_C + o];
    out[(size_t)row * OUT_C + o] = acc;
}

// ---------------------------------------------------------------------------
extern "C" void kernel_launch(void* const* d_in, const int* in_sizes, int n_in,
                              void* d_out, int out_size, void* d_ws, size_t ws_size,
                              hipStream_t stream) {
    const float* x   = (const float*)d_in[0];
    const float* we  = (const float*)d_in[1];
    const float* wc  = (const float*)d_in[2];
    const int*   a1r = (const int*)  d_in[3];
    const int*   a1c = (const int*)  d_in[4];
    const float* a1v = (const float*)d_in[5];
    const int*   a2r = (const int*)  d_in[6];
    const int*   a2c = (const int*)  d_in[7];
    const float* a2v = (const float*)d_in[8];
    float* out = (float*)d_out;

    const int E1 = in_sizes[3];
    const int E2 = in_sizes[6];
    const int n  = in_sizes[0] / IN_C;   // 20000

    // Workspace layout (floats): r0[n*32] r1[n*64] r2[n*128] ip1[n+1] ip2[n+1]
    float* r0 = (float*)d_ws;
    float* r1 = r0 + (size_t)n * 32;
    float* r2 = r1 + (size_t)n * 64;
    int*   ip1 = (int*)(r2 + (size_t)n * 128);
    int*   ip2 = ip1 + (n + 1);

    // 1) embedding
    embed_kernel<<<(n + 7) / 8, 256, 0, stream>>>(x, we, r0, n);

    // 2) CSR indptr for both adjacency matrices
    build_indptr<<<(n + 256) / 256, 256, 0, stream>>>(a1r, E1, ip1, n);
    build_indptr<<<(n + 256) / 256, 256, 0, stream>>>(a2r, E2, ip2, n);

    // 3) level 1: r1 = relu([A1 r0 | A2 r0]),  C=32, out stride 64
    spmm_relu<32><<<(n + 7) / 8, 256, 0, stream>>>(ip1, a1c, a1v, r0, r1, 64, 0,  n);
    spmm_relu<32><<<(n + 7) / 8, 256, 0, stream>>>(ip2, a2c, a2v, r0, r1, 64, 32, n);

    // 4) level 2: r2 = relu([A1 r1 | A2 r1]),  C=64, out stride 128
    spmm_relu<64><<<(n + 3) / 4, 256, 0, stream>>>(ip1, a1c, a1v, r1, r2, 128, 0,  n);
    spmm_relu<64><<<(n + 3) / 4, 256, 0, stream>>>(ip2, a2c, a2v, r1, r2, 128, 64, n);

    // 5) fused concat + classify
    classify_kernel<<<(n + 15) / 16, 256, 0, stream>>>(r0, r1, r2, wc, out, n);
}

// Round 2
// 372.914 us; speedup vs baseline: 1.5659x; 1.5659x over previous
//
#include <hip/hip_runtime.h>

#define IN_C 128
#define HID  32

// ---------------------------------------------------------------------------
// K1: r0 = relu(x @ w_embed)   x:[n,128] w:[128,32] -> r0:[n,32]
// 8 rows/block (256 thr), one thread per (row,h); x read as float4; w in LDS.
// ---------------------------------------------------------------------------
__global__ void embed_kernel(const float* __restrict__ x,
                             const float* __restrict__ w,
                             float* __restrict__ r0, int n) {
    __shared__ float wl[IN_C * HID];
    const int tid = threadIdx.x;
    for (int i = tid; i < IN_C * HID; i += blockDim.x) wl[i] = w[i];
    __syncthreads();
    const int row = blockIdx.x * (blockDim.x / HID) + tid / HID;
    const int h   = tid % HID;
    if (row >= n) return;
    const float4* xr4 = (const float4*)(x + (size_t)row * IN_C);
    float acc = 0.f;
#pragma unroll
    for (int k4 = 0; k4 < IN_C / 4; ++k4) {
        float4 xv = xr4[k4];
        acc += xv.x * wl[(4 * k4 + 0) * HID + h];
        acc += xv.y * wl[(4 * k4 + 1) * HID + h];
        acc += xv.z * wl[(4 * k4 + 2) * HID + h];
        acc += xv.w * wl[(4 * k4 + 3) * HID + h];
    }
    r0[(size_t)row * HID + h] = fmaxf(acc, 0.f);
}

// ---------------------------------------------------------------------------
// K2: CSR indptr from sorted row array via binary search (lower_bound).
// ---------------------------------------------------------------------------
__global__ void build_indptr(const int* __restrict__ rows, int nnz,
                             int* __restrict__ indptr, int n) {
    const int i = blockIdx.x * blockDim.x + threadIdx.x;
    if (i > n) return;
    int lo = 0, hi = nnz;
    while (lo < hi) {
        int mid = (lo + hi) >> 1;
        if (rows[mid] < i) lo = mid + 1; else hi = mid;
    }
    indptr[i] = lo;
}

// ---------------------------------------------------------------------------
// K3: row-group CSR SpMM + ReLU, float4 feature vectorization.
// C/4 lanes per destination row; lane handles features [4f, 4f+3] as float4.
// 4-way edge unroll with 4 independent float4 accumulators for MLP.
// ---------------------------------------------------------------------------
template <int C>
__global__ void spmm_relu_v4(const int* __restrict__ indptr,
                             const int* __restrict__ col,
                             const float* __restrict__ val,
                             const float* __restrict__ xin,
                             float* __restrict__ out,
                             int out_stride, int out_off, int n) {
    constexpr int L = C / 4;                 // lanes per row
    const int row = blockIdx.x * (blockDim.x / L) + threadIdx.x / L;
    const int f4  = (threadIdx.x % L) * 4;   // first feature of this lane
    if (row >= n) return;
    const int s = indptr[row];
    const int e = indptr[row + 1];

    float4 a0 = {0.f, 0.f, 0.f, 0.f};
    float4 a1 = {0.f, 0.f, 0.f, 0.f};
    float4 a2 = {0.f, 0.f, 0.f, 0.f};
    float4 a3 = {0.f, 0.f, 0.f, 0.f};

    int i = s;
    for (; i + 3 < e; i += 4) {
        const int   c0 = col[i],     c1 = col[i + 1];
        const int   c2 = col[i + 2], c3 = col[i + 3];
        const float v0 = val[i],     v1 = val[i + 1];
        const float v2 = val[i + 2], v3 = val[i + 3];
        const float4 x0 = *(const float4*)(xin + (size_t)c0 * C + f4);
        const float4 x1 = *(const float4*)(xin + (size_t)c1 * C + f4);
        const float4 x2 = *(const float4*)(xin + (size_t)c2 * C + f4);
        const float4 x3 = *(const float4*)(xin + (size_t)c3 * C + f4);
        a0.x += v0 * x0.x; a0.y += v0 * x0.y; a0.z += v0 * x0.z; a0.w += v0 * x0.w;
        a1.x += v1 * x1.x; a1.y += v1 * x1.y; a1.z += v1 * x1.z; a1.w += v1 * x1.w;
        a2.x += v2 * x2.x; a2.y += v2 * x2.y; a2.z += v2 * x2.z; a2.w += v2 * x2.w;
        a3.x += v3 * x3.x; a3.y += v3 * x3.y; a3.z += v3 * x3.z; a3.w += v3 * x3.w;
    }
    for (; i < e; ++i) {
        const int   c0 = col[i];
        const float v0 = val[i];
        const float4 x0 = *(const float4*)(xin + (size_t)c0 * C + f4);
        a0.x += v0 * x0.x; a0.y += v0 * x0.y; a0.z += v0 * x0.z; a0.w += v0 * x0.w;
    }

    float4 r;
    r.x = fmaxf(a0.x + a1.x + a2.x + a3.x, 0.f);
    r.y = fmaxf(a0.y + a1.y + a2.y + a3.y, 0.f);
    r.z = fmaxf(a0.z + a1.z + a2.z + a3.z, 0.f);
    r.w = fmaxf(a0.w + a1.w + a2.w + a3.w, 0.f);
    *(float4*)(out + (size_t)row * out_stride + out_off + f4) = r;
}

// ---------------------------------------------------------------------------
// K4: out = [r0 | r1 | r2] @ w_classify   (fused concat; w in LDS, float4 reads)
// ---------------------------------------------------------------------------
#define CDIM 224
#define OUT_C 16
__global__ void classify_kernel(const float* __restrict__ r0,
                                const float* __restrict__ r1,
                                const float* __restrict__ r2,
                                const float* __restrict__ w,
                                float* __restrict__ out, int n) {
    __shared__ float wl[CDIM * OUT_C];
    const int tid = threadIdx.x;
    for (int i = tid; i < CDIM * OUT_C; i += blockDim.x) wl[i] = w[i];
    __syncthreads();
    const int row = blockIdx.x * (blockDim.x / OUT_C) + tid / OUT_C;
    const int o   = tid % OUT_C;
    if (row >= n) return;
    float acc = 0.f;
    const float4* a = (const float4*)(r0 + (size_t)row * 32);
#pragma unroll
    for (int j = 0; j < 8; ++j) {
        float4 v = a[j];
        acc += v.x * wl[(4 * j + 0) * OUT_C + o];
        acc += v.y * wl[(4 * j + 1) * OUT_C + o];
        acc += v.z * wl[(4 * j + 2) * OUT_C + o];
        acc += v.w * wl[(4 * j + 3) * OUT_C + o];
    }
    const float4* b = (const float4*)(r1 + (size_t)row * 64);
#pragma unroll
    for (int j = 0; j < 16; ++j) {
        float4 v = b[j];
        acc += v.x * wl[(32 + 4 * j + 0) * OUT_C + o];
        acc += v.y * wl[(32 + 4 * j + 1) * OUT_C + o];
        acc += v.z * wl[(32 + 4 * j + 2) * OUT_C + o];
        acc += v.w * wl[(32 + 4 * j + 3) * OUT_C + o];
    }
    const float4* c = (const float4*)(r2 + (size_t)row * 128);
#pragma unroll
    for (int j = 0; j < 32; ++j) {
        float4 v = c[j];
        acc += v.x * wl[(96 + 4 * j + 0) * OUT_C + o];
        acc += v.y * wl[(96 + 4 * j + 1) * OUT_C + o];
        acc += v.z * wl[(96 + 4 * j + 2) * OUT_C + o];
        acc += v.w * wl[(96 + 4 * j + 3) * OUT_C + o];
    }
    out[(size_t)row * OUT_C + o] = acc;
}

// ---------------------------------------------------------------------------
extern "C" void kernel_launch(void* const* d_in, const int* in_sizes, int n_in,
                              void* d_out, int out_size, void* d_ws, size_t ws_size,
                              hipStream_t stream) {
    const float* x   = (const float*)d_in[0];
    const float* we  = (const float*)d_in[1];
    const float* wc  = (const float*)d_in[2];
    const int*   a1r = (const int*)  d_in[3];
    const int*   a1c = (const int*)  d_in[4];
    const float* a1v = (const float*)d_in[5];
    const int*   a2r = (const int*)  d_in[6];
    const int*   a2c = (const int*)  d_in[7];
    const float* a2v = (const float*)d_in[8];
    float* out = (float*)d_out;

    const int E1 = in_sizes[3];
    const int E2 = in_sizes[6];
    const int n  = in_sizes[0] / IN_C;   // 20000

    // Workspace layout (floats): r0[n*32] r1[n*64] r2[n*128] ip1[n+1] ip2[n+1]
    float* r0 = (float*)d_ws;
    float* r1 = r0 + (size_t)n * 32;
    float* r2 = r1 + (size_t)n * 64;
    int*   ip1 = (int*)(r2 + (size_t)n * 128);
    int*   ip2 = ip1 + (n + 1);

    // 1) embedding
    embed_kernel<<<(n + 7) / 8, 256, 0, stream>>>(x, we, r0, n);

    // 2) CSR indptr for both adjacency matrices
    build_indptr<<<(n + 256) / 256, 256, 0, stream>>>(a1r, E1, ip1, n);
    build_indptr<<<(n + 256) / 256, 256, 0, stream>>>(a2r, E2, ip2, n);

    // 3) level 1: r1 = relu([A1 r0 | A2 r0]),  C=32 -> 8 lanes/row, 32 rows/block
    spmm_relu_v4<32><<<(n + 31) / 32, 256, 0, stream>>>(ip1, a1c, a1v, r0, r1, 64, 0,  n);
    spmm_relu_v4<32><<<(n + 31) / 32, 256, 0, stream>>>(ip2, a2c, a2v, r0, r1, 64, 32, n);

    // 4) level 2: r2 = relu([A1 r1 | A2 r1]),  C=64 -> 16 lanes/row, 16 rows/block
    spmm_relu_v4<64><<<(n + 15) / 16, 256, 0, stream>>>(ip1, a1c, a1v, r1, r2, 128, 0,  n);
    spmm_relu_v4<64><<<(n + 15) / 16, 256, 0, stream>>>(ip2, a2c, a2v, r1, r2, 128, 64, n);

    // 5) fused concat + classify
    classify_kernel<<<(n + 15) / 16, 256, 0, stream>>>(r0, r1, r2, wc, out, n);
}

// Round 3
// 282.135 us; speedup vs baseline: 2.0697x; 1.3218x over previous
//
#include <hip/hip_runtime.h>

#define IN_C 128
#define HID  32

// ---------------------------------------------------------------------------
// K1: r0 = relu(x @ w_embed)   x:[n,128] w:[128,32] -> r0:[n,32]
// ---------------------------------------------------------------------------
__global__ void embed_kernel(const float* __restrict__ x,
                             const float* __restrict__ w,
                             float* __restrict__ r0, int n) {
    __shared__ float wl[IN_C * HID];
    const int tid = threadIdx.x;
    for (int i = tid; i < IN_C * HID; i += blockDim.x) wl[i] = w[i];
    __syncthreads();
    const int row = blockIdx.x * (blockDim.x / HID) + tid / HID;
    const int h   = tid % HID;
    if (row >= n) return;
    const float4* xr4 = (const float4*)(x + (size_t)row * IN_C);
    float acc = 0.f;
#pragma unroll
    for (int k4 = 0; k4 < IN_C / 4; ++k4) {
        float4 xv = xr4[k4];
        acc += xv.x * wl[(4 * k4 + 0) * HID + h];
        acc += xv.y * wl[(4 * k4 + 1) * HID + h];
        acc += xv.z * wl[(4 * k4 + 2) * HID + h];
        acc += xv.w * wl[(4 * k4 + 3) * HID + h];
    }
    r0[(size_t)row * HID + h] = fmaxf(acc, 0.f);
}

// ---------------------------------------------------------------------------
// K2: both CSR indptrs in one launch (binary search over sorted row arrays).
// ---------------------------------------------------------------------------
__global__ void build_indptr2(const int* __restrict__ r1, int E1, int* __restrict__ ip1,
                              const int* __restrict__ r2, int E2, int* __restrict__ ip2,
                              int n) {
    const int i = blockIdx.x * blockDim.x + threadIdx.x;
    if (i > n) return;
    int lo = 0, hi = E1;
    while (lo < hi) { int m = (lo + hi) >> 1; if (r1[m] < i) lo = m + 1; else hi = m; }
    ip1[i] = lo;
    lo = 0; hi = E2;
    while (lo < hi) { int m = (lo + hi) >> 1; if (r2[m] < i) lo = m + 1; else hi = m; }
    ip2[i] = lo;
}

// ---------------------------------------------------------------------------
// K3: fused-level SpMM + ReLU. One WAVE per destination row.
// Lanes = L feature-lanes (float4 each) x W edge-ways; each way 4-unrolled
// => 4*W gathers in flight per wave-iteration, deg/(4W) iterations.
// Cross-way combine via __shfl_xor (no LDS). Blocks [0,nb1) do A1 -> out col
// offset 0; blocks [nb1,..) do A2 -> out col offset C. out stride = 2*C.
// ---------------------------------------------------------------------------
template <int C>
__global__ void spmm_level(const int* __restrict__ ip1, const int* __restrict__ col1,
                           const float* __restrict__ val1,
                           const int* __restrict__ ip2, const int* __restrict__ col2,
                           const float* __restrict__ val2,
                           const float* __restrict__ xin, float* __restrict__ out,
                           int n, int nb1) {
    constexpr int L = C / 4;     // feature lanes per row
    constexpr int W = 64 / L;    // edge ways
    const int lane = threadIdx.x & 63;
    const int wave = threadIdx.x >> 6;

    int bid = blockIdx.x;
    const int*   ip;  const int* col; const float* val; int off;
    if (bid >= nb1) { bid -= nb1; ip = ip2; col = col2; val = val2; off = C; }
    else            {             ip = ip1; col = col1; val = val1; off = 0; }

    const int row = bid * 4 + wave;          // 4 waves (rows) per 256-thr block
    if (row >= n) return;

    const int fl  = lane % L;
    const int way = lane / L;
    const int f4  = fl * 4;

    const int s = ip[row];
    const int e = ip[row + 1];
    const int nE = e - s;
    const int iters = nE / (W * 4);

    float4 a0 = {0.f,0.f,0.f,0.f}, a1 = {0.f,0.f,0.f,0.f};
    float4 a2 = {0.f,0.f,0.f,0.f}, a3 = {0.f,0.f,0.f,0.f};

    for (int i = 0; i < iters; ++i) {
        const int base = s + (i * W + way) * 4;
        const int   c0 = col[base],     c1 = col[base + 1];
        const int   c2 = col[base + 2], c3 = col[base + 3];
        const float v0 = val[base],     v1 = val[base + 1];
        const float v2 = val[base + 2], v3 = val[base + 3];
        const float4 x0 = *(const float4*)(xin + (size_t)c0 * C + f4);
        const float4 x1 = *(const float4*)(xin + (size_t)c1 * C + f4);
        const float4 x2 = *(const float4*)(xin + (size_t)c2 * C + f4);
        const float4 x3 = *(const float4*)(xin + (size_t)c3 * C + f4);
        a0.x += v0 * x0.x; a0.y += v0 * x0.y; a0.z += v0 * x0.z; a0.w += v0 * x0.w;
        a1.x += v1 * x1.x; a1.y += v1 * x1.y; a1.z += v1 * x1.z; a1.w += v1 * x1.w;
        a2.x += v2 * x2.x; a2.y += v2 * x2.y; a2.z += v2 * x2.z; a2.w += v2 * x2.w;
        a3.x += v3 * x3.x; a3.y += v3 * x3.y; a3.z += v3 * x3.z; a3.w += v3 * x3.w;
    }
    // tail: each way takes every W-th remaining edge
    for (int idx = s + iters * W * 4 + way; idx < e; idx += W) {
        const int   c = col[idx];
        const float v = val[idx];
        const float4 xv = *(const float4*)(xin + (size_t)c * C + f4);
        a0.x += v * xv.x; a0.y += v * xv.y; a0.z += v * xv.z; a0.w += v * xv.w;
    }

    float4 a;
    a.x = a0.x + a1.x + a2.x + a3.x;
    a.y = a0.y + a1.y + a2.y + a3.y;
    a.z = a0.z + a1.z + a2.z + a3.z;
    a.w = a0.w + a1.w + a2.w + a3.w;

    // cross-way in-register reduction
#pragma unroll
    for (int mask = L; mask < 64; mask <<= 1) {
        a.x += __shfl_xor(a.x, mask, 64);
        a.y += __shfl_xor(a.y, mask, 64);
        a.z += __shfl_xor(a.z, mask, 64);
        a.w += __shfl_xor(a.w, mask, 64);
    }

    if (way == 0) {
        float4 r;
        r.x = fmaxf(a.x, 0.f); r.y = fmaxf(a.y, 0.f);
        r.z = fmaxf(a.z, 0.f); r.w = fmaxf(a.w, 0.f);
        *(float4*)(out + (size_t)row * (2 * C) + off + f4) = r;
    }
}

// ---------------------------------------------------------------------------
// K4: out = [r0 | r1 | r2] @ w_classify   (fused concat; w in LDS, float4 reads)
// ---------------------------------------------------------------------------
#define CDIM 224
#define OUT_C 16
__global__ void classify_kernel(const float* __restrict__ r0,
                                const float* __restrict__ r1,
                                const float* __restrict__ r2,
                                const float* __restrict__ w,
                                float* __restrict__ out, int n) {
    __shared__ float wl[CDIM * OUT_C];
    const int tid = threadIdx.x;
    for (int i = tid; i < CDIM * OUT_C; i += blockDim.x) wl[i] = w[i];
    __syncthreads();
    const int row = blockIdx.x * (blockDim.x / OUT_C) + tid / OUT_C;
    const int o   = tid % OUT_C;
    if (row >= n) return;
    float acc = 0.f;
    const float4* a = (const float4*)(r0 + (size_t)row * 32);
#pragma unroll
    for (int j = 0; j < 8; ++j) {
        float4 v = a[j];
        acc += v.x * wl[(4 * j + 0) * OUT_C + o];
        acc += v.y * wl[(4 * j + 1) * OUT_C + o];
        acc += v.z * wl[(4 * j + 2) * OUT_C + o];
        acc += v.w * wl[(4 * j + 3) * OUT_C + o];
    }
    const float4* b = (const float4*)(r1 + (size_t)row * 64);
#pragma unroll
    for (int j = 0; j < 16; ++j) {
        float4 v = b[j];
        acc += v.x * wl[(32 + 4 * j + 0) * OUT_C + o];
        acc += v.y * wl[(32 + 4 * j + 1) * OUT_C + o];
        acc += v.z * wl[(32 + 4 * j + 2) * OUT_C + o];
        acc += v.w * wl[(32 + 4 * j + 3) * OUT_C + o];
    }
    const float4* c = (const float4*)(r2 + (size_t)row * 128);
#pragma unroll
    for (int j = 0; j < 32; ++j) {
        float4 v = c[j];
        acc += v.x * wl[(96 + 4 * j + 0) * OUT_C + o];
        acc += v.y * wl[(96 + 4 * j + 1) * OUT_C + o];
        acc += v.z * wl[(96 + 4 * j + 2) * OUT_C + o];
        acc += v.w * wl[(96 + 4 * j + 3) * OUT_C + o];
    }
    out[(size_t)row * OUT_C + o] = acc;
}

// ---------------------------------------------------------------------------
extern "C" void kernel_launch(void* const* d_in, const int* in_sizes, int n_in,
                              void* d_out, int out_size, void* d_ws, size_t ws_size,
                              hipStream_t stream) {
    const float* x   = (const float*)d_in[0];
    const float* we  = (const float*)d_in[1];
    const float* wc  = (const float*)d_in[2];
    const int*   a1r = (const int*)  d_in[3];
    const int*   a1c = (const int*)  d_in[4];
    const float* a1v = (const float*)d_in[5];
    const int*   a2r = (const int*)  d_in[6];
    const int*   a2c = (const int*)  d_in[7];
    const float* a2v = (const float*)d_in[8];
    float* out = (float*)d_out;

    const int E1 = in_sizes[3];
    const int E2 = in_sizes[6];
    const int n  = in_sizes[0] / IN_C;   // 20000

    // Workspace layout (floats): r0[n*32] r1[n*64] r2[n*128] ip1[n+1] ip2[n+1]
    float* r0 = (float*)d_ws;
    float* r1 = r0 + (size_t)n * 32;
    float* r2 = r1 + (size_t)n * 64;
    int*   ip1 = (int*)(r2 + (size_t)n * 128);
    int*   ip2 = ip1 + (n + 1);

    // 1) embedding
    embed_kernel<<<(n + 7) / 8, 256, 0, stream>>>(x, we, r0, n);

    // 2) both CSR indptrs
    build_indptr2<<<(n + 256) / 256, 256, 0, stream>>>(a1r, E1, ip1, a2r, E2, ip2, n);

    // 3) level 1: r1 = relu([A1 r0 | A2 r0]); one wave per row, fused A1+A2
    {
        const int nb = (n + 3) / 4;          // 4 rows (waves) per block
        spmm_level<32><<<2 * nb, 256, 0, stream>>>(ip1, a1c, a1v, ip2, a2c, a2v,
                                                   r0, r1, n, nb);
    }
    // 4) level 2: r2 = relu([A1 r1 | A2 r1])
    {
        const int nb = (n + 3) / 4;
        spmm_level<64><<<2 * nb, 256, 0, stream>>>(ip1, a1c, a1v, ip2, a2c, a2v,
                                                   r1, r2, n, nb);
    }

    // 5) fused concat + classify
    classify_kernel<<<(n + 15) / 16, 256, 0, stream>>>(r0, r1, r2, wc, out, n);
}

// Round 4
// 236.705 us; speedup vs baseline: 2.4669x; 1.1919x over previous
//
#include <hip/hip_runtime.h>

typedef unsigned int uint;
typedef unsigned short ushort;

#define IN_C 128
#define HID  32

// ---- bf16 helpers (fp32 accumulate everywhere; RNE on store) --------------
__device__ __forceinline__ float bf_lo(uint u) { return __uint_as_float(u << 16); }
__device__ __forceinline__ float bf_hi(uint u) { return __uint_as_float(u & 0xffff0000u); }
__device__ __forceinline__ uint  f2bf(float f) {
    uint u = __float_as_uint(f);
    return (u + 0x7fffu + ((u >> 16) & 1u)) >> 16;   // RNE; inputs are finite
}

// ---------------------------------------------------------------------------
// K1: r0 = relu(x @ w_embed) -> bf16 [n,32]. 16 thr/row, 2 features each.
// ---------------------------------------------------------------------------
__global__ void embed_kernel(const float* __restrict__ x,
                             const float* __restrict__ w,
                             ushort* __restrict__ r0, int n) {
    __shared__ float wl[IN_C * HID];
    const int tid = threadIdx.x;
    for (int i = tid; i < IN_C * HID; i += blockDim.x) wl[i] = w[i];
    __syncthreads();
    const int row = blockIdx.x * 16 + tid / 16;
    const int h0  = (tid % 16) * 2;
    if (row >= n) return;
    const float4* xr = (const float4*)(x + (size_t)row * IN_C);
    float a0 = 0.f, a1 = 0.f;
#pragma unroll
    for (int k4 = 0; k4 < IN_C / 4; ++k4) {
        float4 xv = xr[k4];
        a0 += xv.x * wl[(4*k4+0)*HID + h0];     a1 += xv.x * wl[(4*k4+0)*HID + h0+1];
        a0 += xv.y * wl[(4*k4+1)*HID + h0];     a1 += xv.y * wl[(4*k4+1)*HID + h0+1];
        a0 += xv.z * wl[(4*k4+2)*HID + h0];     a1 += xv.z * wl[(4*k4+2)*HID + h0+1];
        a0 += xv.w * wl[(4*k4+3)*HID + h0];     a1 += xv.w * wl[(4*k4+3)*HID + h0+1];
    }
    uint p = f2bf(fmaxf(a0, 0.f)) | (f2bf(fmaxf(a1, 0.f)) << 16);
    ((uint*)r0)[(size_t)row * 16 + (tid % 16)] = p;
}

// ---------------------------------------------------------------------------
// K2: both CSR indptrs in one launch (binary search over sorted row arrays).
// ---------------------------------------------------------------------------
__global__ void build_indptr2(const int* __restrict__ r1, int E1, int* __restrict__ ip1,
                              const int* __restrict__ r2, int E2, int* __restrict__ ip2,
                              int n) {
    const int i = blockIdx.x * blockDim.x + threadIdx.x;
    if (i > n) return;
    int lo = 0, hi = E1;
    while (lo < hi) { int m = (lo + hi) >> 1; if (r1[m] < i) lo = m + 1; else hi = m; }
    ip1[i] = lo;
    lo = 0; hi = E2;
    while (lo < hi) { int m = (lo + hi) >> 1; if (r2[m] < i) lo = m + 1; else hi = m; }
    ip2[i] = lo;
}

// ---------------------------------------------------------------------------
// K3: fused-level SpMM + ReLU, bf16 features / fp32 accumulate.
// One wave per destination row. L = C/8 feature-lanes (uint4 = 8 bf16 feats)
// x W = 64/L edge-ways; each way loads 4 edges as int4/float4 (aligned via
// per-row fixup) => 4W edges per wave-iteration, 6 VMEM instr per iteration.
// Cross-way combine via __shfl_xor. Blocks [0,nb1) = A1 (col off 0),
// [nb1,..) = A2 (col off C). out is bf16, stride 2C.
// ---------------------------------------------------------------------------
template <int C>
__global__ __launch_bounds__(256) void spmm_level(
        const int* __restrict__ ip1, const int* __restrict__ col1,
        const float* __restrict__ val1,
        const int* __restrict__ ip2, const int* __restrict__ col2,
        const float* __restrict__ val2,
        const ushort* __restrict__ xin, ushort* __restrict__ out,
        int n, int nb1) {
    constexpr int L = C / 8;     // feature lanes per row
    constexpr int W = 64 / L;    // edge ways
    const int lane = threadIdx.x & 63;
    const int wave = threadIdx.x >> 6;

    int bid = blockIdx.x;
    const int* ip; const int* col; const float* val; int off;
    if (bid >= nb1) { bid -= nb1; ip = ip2; col = col2; val = val2; off = C; }
    else            {             ip = ip1; col = col1; val = val1; off = 0; }

    const int row = bid * 4 + wave;          // 4 waves (rows) per 256-thr block
    if (row >= n) return;

    const int fl  = lane % L;
    const int way = lane / L;
    const ushort* xbase = xin + fl * 8;

    float acc[8];
#pragma unroll
    for (int j = 0; j < 8; ++j) acc[j] = 0.f;

    const int s = ip[row];
    const int e = ip[row + 1];
    int sv = (s + 3) & ~3;                   // 16B-aligned start for int4 loads
    if (sv > e) sv = e;
    const int nv = (e - sv) / (4 * W);

    auto edge = [&](int c, float v) {
        const uint4 u = *(const uint4*)(xbase + (size_t)c * C);
        acc[0] += v * bf_lo(u.x);  acc[1] += v * bf_hi(u.x);
        acc[2] += v * bf_lo(u.y);  acc[3] += v * bf_hi(u.y);
        acc[4] += v * bf_lo(u.z);  acc[5] += v * bf_hi(u.z);
        acc[6] += v * bf_lo(u.w);  acc[7] += v * bf_hi(u.w);
    };

    // head (<=3 unaligned edges)
    for (int idx = s + way; idx < sv; idx += W) edge(col[idx], val[idx]);
    // aligned vector body
    for (int i = 0; i < nv; ++i) {
        const int base = sv + (i * W + way) * 4;
        const int4   cc = *(const int4*)  (col + base);
        const float4 vv = *(const float4*)(val + base);
        edge(cc.x, vv.x); edge(cc.y, vv.y); edge(cc.z, vv.z); edge(cc.w, vv.w);
    }
    // tail
    for (int idx = sv + nv * 4 * W + way; idx < e; idx += W) edge(col[idx], val[idx]);

    // cross-way in-register reduction
#pragma unroll
    for (int m = L; m < 64; m <<= 1)
#pragma unroll
        for (int j = 0; j < 8; ++j) acc[j] += __shfl_xor(acc[j], m, 64);

    if (way == 0) {
        uint4 p;
        p.x = f2bf(fmaxf(acc[0], 0.f)) | (f2bf(fmaxf(acc[1], 0.f)) << 16);
        p.y = f2bf(fmaxf(acc[2], 0.f)) | (f2bf(fmaxf(acc[3], 0.f)) << 16);
        p.z = f2bf(fmaxf(acc[4], 0.f)) | (f2bf(fmaxf(acc[5], 0.f)) << 16);
        p.w = f2bf(fmaxf(acc[6], 0.f)) | (f2bf(fmaxf(acc[7], 0.f)) << 16);
        *(uint4*)(out + (size_t)row * (2 * C) + off + fl * 8) = p;
    }
}

// ---------------------------------------------------------------------------
// K4: out = [r0 | r1 | r2] @ w_classify  (bf16 features, fp32 weights in LDS)
// 16 thr/row (one per output col), 16 rows per 256-thr block.
// ---------------------------------------------------------------------------
#define CDIM 224
#define OUT_C 16
__global__ void classify_kernel(const ushort* __restrict__ r0,
                                const ushort* __restrict__ r1,
                                const ushort* __restrict__ r2,
                                const float* __restrict__ w,
                                float* __restrict__ out, int n) {
    __shared__ float wl[CDIM * OUT_C];
    const int tid = threadIdx.x;
    for (int i = tid; i < CDIM * OUT_C; i += blockDim.x) wl[i] = w[i];
    __syncthreads();
    const int row = blockIdx.x * 16 + tid / 16;
    const int o   = tid % 16;
    if (row >= n) return;
    float acc = 0.f;

    const uint4* a = (const uint4*)(r0 + (size_t)row * 32);
#pragma unroll
    for (int q = 0; q < 4; ++q) {
        uint4 u = a[q]; int j = q * 8;
        acc += bf_lo(u.x) * wl[(j+0)*OUT_C + o];  acc += bf_hi(u.x) * wl[(j+1)*OUT_C + o];
        acc += bf_lo(u.y) * wl[(j+2)*OUT_C + o];  acc += bf_hi(u.y) * wl[(j+3)*OUT_C + o];
        acc += bf_lo(u.z) * wl[(j+4)*OUT_C + o];  acc += bf_hi(u.z) * wl[(j+5)*OUT_C + o];
        acc += bf_lo(u.w) * wl[(j+6)*OUT_C + o];  acc += bf_hi(u.w) * wl[(j+7)*OUT_C + o];
    }
    const uint4* b = (const uint4*)(r1 + (size_t)row * 64);
#pragma unroll
    for (int q = 0; q < 8; ++q) {
        uint4 u = b[q]; int j = 32 + q * 8;
        acc += bf_lo(u.x) * wl[(j+0)*OUT_C + o];  acc += bf_hi(u.x) * wl[(j+1)*OUT_C + o];
        acc += bf_lo(u.y) * wl[(j+2)*OUT_C + o];  acc += bf_hi(u.y) * wl[(j+3)*OUT_C + o];
        acc += bf_lo(u.z) * wl[(j+4)*OUT_C + o];  acc += bf_hi(u.z) * wl[(j+5)*OUT_C + o];
        acc += bf_lo(u.w) * wl[(j+6)*OUT_C + o];  acc += bf_hi(u.w) * wl[(j+7)*OUT_C + o];
    }
    const uint4* c = (const uint4*)(r2 + (size_t)row * 128);
#pragma unroll
    for (int q = 0; q < 16; ++q) {
        uint4 u = c[q]; int j = 96 + q * 8;
        acc += bf_lo(u.x) * wl[(j+0)*OUT_C + o];  acc += bf_hi(u.x) * wl[(j+1)*OUT_C + o];
        acc += bf_lo(u.y) * wl[(j+2)*OUT_C + o];  acc += bf_hi(u.y) * wl[(j+3)*OUT_C + o];
        acc += bf_lo(u.z) * wl[(j+4)*OUT_C + o];  acc += bf_hi(u.z) * wl[(j+5)*OUT_C + o];
        acc += bf_lo(u.w) * wl[(j+6)*OUT_C + o];  acc += bf_hi(u.w) * wl[(j+7)*OUT_C + o];
    }
    out[(size_t)row * OUT_C + o] = acc;
}

// ---------------------------------------------------------------------------
extern "C" void kernel_launch(void* const* d_in, const int* in_sizes, int n_in,
                              void* d_out, int out_size, void* d_ws, size_t ws_size,
                              hipStream_t stream) {
    const float* x   = (const float*)d_in[0];
    const float* we  = (const float*)d_in[1];
    const float* wc  = (const float*)d_in[2];
    const int*   a1r = (const int*)  d_in[3];
    const int*   a1c = (const int*)  d_in[4];
    const float* a1v = (const float*)d_in[5];
    const int*   a2r = (const int*)  d_in[6];
    const int*   a2c = (const int*)  d_in[7];
    const float* a2v = (const float*)d_in[8];
    float* out = (float*)d_out;

    const int E1 = in_sizes[3];
    const int E2 = in_sizes[6];
    const int n  = in_sizes[0] / IN_C;   // 20000

    // Workspace (bf16 features): r0[n*32] r1[n*64] r2[n*128], then ip1/ip2
    ushort* r0 = (ushort*)d_ws;
    ushort* r1 = r0 + (size_t)n * 32;
    ushort* r2 = r1 + (size_t)n * 64;
    int*   ip1 = (int*)(r2 + (size_t)n * 128);
    int*   ip2 = ip1 + (n + 1);

    // 1) embedding
    embed_kernel<<<(n + 15) / 16, 256, 0, stream>>>(x, we, r0, n);

    // 2) both CSR indptrs
    build_indptr2<<<(n + 256) / 256, 256, 0, stream>>>(a1r, E1, ip1, a2r, E2, ip2, n);

    const int nb = (n + 3) / 4;          // 4 rows (waves) per block

    // 3) level 1: r1 = relu([A1 r0 | A2 r0]);  C=32 -> L=4 lanes, W=16 ways
    spmm_level<32><<<2 * nb, 256, 0, stream>>>(ip1, a1c, a1v, ip2, a2c, a2v,
                                               r0, r1, n, nb);
    // 4) level 2: r2 = relu([A1 r1 | A2 r1]);  C=64 -> L=8 lanes, W=8 ways
    spmm_level<64><<<2 * nb, 256, 0, stream>>>(ip1, a1c, a1v, ip2, a2c, a2v,
                                               r1, r2, n, nb);

    // 5) fused concat + classify
    classify_kernel<<<(n + 15) / 16, 256, 0, stream>>>(r0, r1, r2, wc, out, n);
}

// Round 5
// 235.963 us; speedup vs baseline: 2.4747x; 1.0031x over previous
//
#include <hip/hip_runtime.h>

typedef unsigned int uint;
typedef unsigned short ushort;

#define IN_C 128
#define HID  32

// ---- bf16 helpers (fp32 accumulate everywhere; RNE on store) --------------
__device__ __forceinline__ float bf_lo(uint u) { return __uint_as_float(u << 16); }
__device__ __forceinline__ float bf_hi(uint u) { return __uint_as_float(u & 0xffff0000u); }
__device__ __forceinline__ uint  f2bf(float f) {
    uint u = __float_as_uint(f);
    return (u + 0x7fffu + ((u >> 16) & 1u)) >> 16;   // RNE; inputs are finite
}

// ---------------------------------------------------------------------------
// K1: fused prep: blocks [0,nbE) compute r0 = relu(x @ w_embed) -> bf16;
// blocks [nbE,..) build both CSR indptrs by binary search.
// ---------------------------------------------------------------------------
__global__ void prep_kernel(const float* __restrict__ x,
                            const float* __restrict__ w,
                            ushort* __restrict__ r0,
                            const int* __restrict__ a1r, int E1, int* __restrict__ ip1,
                            const int* __restrict__ a2r, int E2, int* __restrict__ ip2,
                            int n, int nbE) {
    __shared__ float wl[IN_C * HID];
    const int tid = threadIdx.x;
    if (blockIdx.x < nbE) {
        for (int i = tid; i < IN_C * HID; i += blockDim.x) wl[i] = w[i];
        __syncthreads();
        const int row = blockIdx.x * 16 + tid / 16;
        const int h0  = (tid % 16) * 2;
        if (row >= n) return;
        const float4* xr = (const float4*)(x + (size_t)row * IN_C);
        float a0 = 0.f, a1 = 0.f;
#pragma unroll
        for (int k4 = 0; k4 < IN_C / 4; ++k4) {
            float4 xv = xr[k4];
            a0 += xv.x * wl[(4*k4+0)*HID + h0];  a1 += xv.x * wl[(4*k4+0)*HID + h0+1];
            a0 += xv.y * wl[(4*k4+1)*HID + h0];  a1 += xv.y * wl[(4*k4+1)*HID + h0+1];
            a0 += xv.z * wl[(4*k4+2)*HID + h0];  a1 += xv.z * wl[(4*k4+2)*HID + h0+1];
            a0 += xv.w * wl[(4*k4+3)*HID + h0];  a1 += xv.w * wl[(4*k4+3)*HID + h0+1];
        }
        uint p = f2bf(fmaxf(a0, 0.f)) | (f2bf(fmaxf(a1, 0.f)) << 16);
        ((uint*)r0)[(size_t)row * 16 + (tid % 16)] = p;
    } else {
        const int i = (blockIdx.x - nbE) * 256 + tid;
        if (i > n) return;
        int lo = 0, hi = E1;
        while (lo < hi) { int m = (lo + hi) >> 1; if (a1r[m] < i) lo = m + 1; else hi = m; }
        ip1[i] = lo;
        lo = 0; hi = E2;
        while (lo < hi) { int m = (lo + hi) >> 1; if (a2r[m] < i) lo = m + 1; else hi = m; }
        ip2[i] = lo;
    }
}

// ---------------------------------------------------------------------------
// K2: fused-level SpMM + ReLU, bf16 features / fp32 accumulate.
// ROWS rows per wave; per row: L = C/8 feature-lanes (uint4 = 8 bf16 feats)
// x W = (64/ROWS)/L edge-ways, 4-edge vector chunks per way.
// Software pipeline: edge chunks prefetched 2 iters ahead, gathers issued
// 1 iter ahead -> FMAs consume in-flight data. Cross-way __shfl_xor combine.
// Blocks [0,nb2) = A2 (heavy first, out col off C); rest = A1 (off 0).
// ---------------------------------------------------------------------------
template <int C, int ROWS>
__global__ __launch_bounds__(256) void spmm_level(
        const int* __restrict__ ip1, const int* __restrict__ col1,
        const float* __restrict__ val1,
        const int* __restrict__ ip2, const int* __restrict__ col2,
        const float* __restrict__ val2,
        const ushort* __restrict__ xin, ushort* __restrict__ out,
        int n, int nb2) {
    constexpr int L    = C / 8;        // feature lanes per row
    constexpr int SUBL = 64 / ROWS;    // lanes per row
    constexpr int W    = SUBL / L;     // edge ways per row
    const int lane = threadIdx.x & 63;
    const int wave = threadIdx.x >> 6;
    const int sub  = lane / SUBL;
    const int li   = lane % SUBL;
    const int fl   = li % L;
    const int way  = li / L;

    int bid = blockIdx.x;
    const int* ip; const int* col; const float* val; int off;
    if (bid < nb2) {             ip = ip2; col = col2; val = val2; off = C; }
    else           { bid -= nb2; ip = ip1; col = col1; val = val1; off = 0; }

    const int row = (bid * 4 + wave) * ROWS + sub;
    if (row >= n) return;

    const ushort* xbase = xin + fl * 8;
    float acc[8];
#pragma unroll
    for (int j = 0; j < 8; ++j) acc[j] = 0.f;

    auto gat = [&](int c) -> uint4 {
        return *(const uint4*)(xbase + (size_t)c * C);
    };
    auto fmadd = [&](const uint4& u, float v) {
        acc[0] += v * bf_lo(u.x); acc[1] += v * bf_hi(u.x);
        acc[2] += v * bf_lo(u.y); acc[3] += v * bf_hi(u.y);
        acc[4] += v * bf_lo(u.z); acc[5] += v * bf_hi(u.z);
        acc[6] += v * bf_lo(u.w); acc[7] += v * bf_hi(u.w);
    };

    const int s = ip[row];
    const int e = ip[row + 1];
    int sv = (s + 3) & ~3; if (sv > e) sv = e;     // 16B-align vector body
    const int nv = (e - sv) / (4 * W);

    // unaligned head (<=3 edges)
    for (int idx = s + way; idx < sv; idx += W) fmadd(gat(col[idx]), val[idx]);

    // pipelined aligned body
    const int4*   cp = (const int4*)  (col + sv) + way;
    const float4* vp = (const float4*)(val + sv) + way;
    int4 ccA, ccB; float4 vvA, vvB, vcur;
    uint4 g0, g1, g2, g3;
    if (nv > 0) {
        ccA = cp[0]; vvA = vp[0];
        g0 = gat(ccA.x); g1 = gat(ccA.y); g2 = gat(ccA.z); g3 = gat(ccA.w);
        vcur = vvA;
        if (nv > 1) { ccA = cp[W];     vvA = vp[W]; }
        if (nv > 2) { ccB = cp[2 * W]; vvB = vp[2 * W]; }
        else        { ccB = ccA;       vvB = vvA; }
    }
    for (int i = 0; i + 1 < nv; ++i) {
        // issue gathers for iter i+1 (edges already in flight >=1 iter)
        uint4 h0 = gat(ccA.x), h1 = gat(ccA.y), h2 = gat(ccA.z), h3 = gat(ccA.w);
        float4 vnxt = vvA;
        ccA = ccB; vvA = vvB;
        const int pidx = (i + 3 < nv) ? (i + 3) : (nv - 1);
        ccB = cp[pidx * W]; vvB = vp[pidx * W];
        // consume gathers for iter i
        fmadd(g0, vcur.x); fmadd(g1, vcur.y); fmadd(g2, vcur.z); fmadd(g3, vcur.w);
        g0 = h0; g1 = h1; g2 = h2; g3 = h3; vcur = vnxt;
    }
    if (nv > 0) {
        fmadd(g0, vcur.x); fmadd(g1, vcur.y); fmadd(g2, vcur.z); fmadd(g3, vcur.w);
    }

    // tail
    for (int idx = sv + nv * 4 * W + way; idx < e; idx += W)
        fmadd(gat(col[idx]), val[idx]);

    // cross-way in-register reduction (stays within each row's subgroup)
#pragma unroll
    for (int m = L; m < SUBL; m <<= 1)
#pragma unroll
        for (int j = 0; j < 8; ++j) acc[j] += __shfl_xor(acc[j], m, 64);

    if (way == 0) {
        uint4 p;
        p.x = f2bf(fmaxf(acc[0],0.f)) | (f2bf(fmaxf(acc[1],0.f)) << 16);
        p.y = f2bf(fmaxf(acc[2],0.f)) | (f2bf(fmaxf(acc[3],0.f)) << 16);
        p.z = f2bf(fmaxf(acc[4],0.f)) | (f2bf(fmaxf(acc[5],0.f)) << 16);
        p.w = f2bf(fmaxf(acc[6],0.f)) | (f2bf(fmaxf(acc[7],0.f)) << 16);
        *(uint4*)(out + (size_t)row * (2 * C) + off + fl * 8) = p;
    }
}

// ---------------------------------------------------------------------------
// K3: out = [r0 | r1 | r2] @ w_classify  (bf16 features, fp32 weights in LDS)
// ---------------------------------------------------------------------------
#define CDIM 224
#define OUT_C 16
__global__ void classify_kernel(const ushort* __restrict__ r0,
                                const ushort* __restrict__ r1,
                                const ushort* __restrict__ r2,
                                const float* __restrict__ w,
                                float* __restrict__ out, int n) {
    __shared__ float wl[CDIM * OUT_C];
    const int tid = threadIdx.x;
    for (int i = tid; i < CDIM * OUT_C; i += blockDim.x) wl[i] = w[i];
    __syncthreads();
    const int row = blockIdx.x * 16 + tid / 16;
    const int o   = tid % 16;
    if (row >= n) return;
    float acc = 0.f;

    const uint4* a = (const uint4*)(r0 + (size_t)row * 32);
#pragma unroll
    for (int q = 0; q < 4; ++q) {
        uint4 u = a[q]; int j = q * 8;
        acc += bf_lo(u.x) * wl[(j+0)*OUT_C + o];  acc += bf_hi(u.x) * wl[(j+1)*OUT_C + o];
        acc += bf_lo(u.y) * wl[(j+2)*OUT_C + o];  acc += bf_hi(u.y) * wl[(j+3)*OUT_C + o];
        acc += bf_lo(u.z) * wl[(j+4)*OUT_C + o];  acc += bf_hi(u.z) * wl[(j+5)*OUT_C + o];
        acc += bf_lo(u.w) * wl[(j+6)*OUT_C + o];  acc += bf_hi(u.w) * wl[(j+7)*OUT_C + o];
    }
    const uint4* b = (const uint4*)(r1 + (size_t)row * 64);
#pragma unroll
    for (int q = 0; q < 8; ++q) {
        uint4 u = b[q]; int j = 32 + q * 8;
        acc += bf_lo(u.x) * wl[(j+0)*OUT_C + o];  acc += bf_hi(u.x) * wl[(j+1)*OUT_C + o];
        acc += bf_lo(u.y) * wl[(j+2)*OUT_C + o];  acc += bf_hi(u.y) * wl[(j+3)*OUT_C + o];
        acc += bf_lo(u.z) * wl[(j+4)*OUT_C + o];  acc += bf_hi(u.z) * wl[(j+5)*OUT_C + o];
        acc += bf_lo(u.w) * wl[(j+6)*OUT_C + o];  acc += bf_hi(u.w) * wl[(j+7)*OUT_C + o];
    }
    const uint4* c = (const uint4*)(r2 + (size_t)row * 128);
#pragma unroll
    for (int q = 0; q < 16; ++q) {
        uint4 u = c[q]; int j = 96 + q * 8;
        acc += bf_lo(u.x) * wl[(j+0)*OUT_C + o];  acc += bf_hi(u.x) * wl[(j+1)*OUT_C + o];
        acc += bf_lo(u.y) * wl[(j+2)*OUT_C + o];  acc += bf_hi(u.y) * wl[(j+3)*OUT_C + o];
        acc += bf_lo(u.z) * wl[(j+4)*OUT_C + o];  acc += bf_hi(u.z) * wl[(j+5)*OUT_C + o];
        acc += bf_lo(u.w) * wl[(j+6)*OUT_C + o];  acc += bf_hi(u.w) * wl[(j+7)*OUT_C + o];
    }
    out[(size_t)row * OUT_C + o] = acc;
}

// ---------------------------------------------------------------------------
extern "C" void kernel_launch(void* const* d_in, const int* in_sizes, int n_in,
                              void* d_out, int out_size, void* d_ws, size_t ws_size,
                              hipStream_t stream) {
    const float* x   = (const float*)d_in[0];
    const float* we  = (const float*)d_in[1];
    const float* wc  = (const float*)d_in[2];
    const int*   a1r = (const int*)  d_in[3];
    const int*   a1c = (const int*)  d_in[4];
    const float* a1v = (const float*)d_in[5];
    const int*   a2r = (const int*)  d_in[6];
    const int*   a2c = (const int*)  d_in[7];
    const float* a2v = (const float*)d_in[8];
    float* out = (float*)d_out;

    const int E1 = in_sizes[3];
    const int E2 = in_sizes[6];
    const int n  = in_sizes[0] / IN_C;   // 20000

    // Workspace (bf16 features): r0[n*32] r1[n*64] r2[n*128], then ip1/ip2
    ushort* r0 = (ushort*)d_ws;
    ushort* r1 = r0 + (size_t)n * 32;
    ushort* r2 = r1 + (size_t)n * 64;
    int*   ip1 = (int*)(r2 + (size_t)n * 128);
    int*   ip2 = ip1 + (n + 1);

    // 1) fused embed + indptr
    {
        const int nbE = (n + 15) / 16;
        const int nbI = (n + 1 + 255) / 256;
        prep_kernel<<<nbE + nbI, 256, 0, stream>>>(x, we, r0, a1r, E1, ip1,
                                                   a2r, E2, ip2, n, nbE);
    }

    // 2) level 1: r1 = relu([A1 r0 | A2 r0]); C=32, 2 rows/wave -> 8 rows/block
    {
        const int nb = (n + 7) / 8;
        spmm_level<32, 2><<<2 * nb, 256, 0, stream>>>(ip1, a1c, a1v, ip2, a2c, a2v,
                                                      r0, r1, n, nb);
    }
    // 3) level 2: r2 = relu([A1 r1 | A2 r1]); C=64, 1 row/wave -> 4 rows/block
    {
        const int nb = (n + 3) / 4;
        spmm_level<64, 1><<<2 * nb, 256, 0, stream>>>(ip1, a1c, a1v, ip2, a2c, a2v,
                                                      r1, r2, n, nb);
    }

    // 4) fused concat + classify
    classify_kernel<<<(n + 15) / 16, 256, 0, stream>>>(r0, r1, r2, wc, out, n);
}